// Round 5
// baseline (549.791 us; speedup 1.0000x reference)
//
#include <hip/hip_runtime.h>
#include <hip/hip_bf16.h>
#include <stdint.h>

// Problem constants
#define Hn 16
#define Tn 2048
#define En 1024
#define Dh 64

typedef __bf16 bf16x8 __attribute__((ext_vector_type(8)));
typedef float f32x4 __attribute__((ext_vector_type(4)));
typedef unsigned short u16;
typedef u16 u16x8 __attribute__((ext_vector_type(8)));

#define SCALE_Q 0.18033688f   // log2(e)/8 folded into Q at projection time

__device__ __forceinline__ u16 f2bf(float f) {
  union { float f; uint32_t u; } v; v.f = f;
  uint32_t r = v.u + 0x7fffu + ((v.u >> 16) & 1u);   // RNE
  return (u16)(r >> 16);
}

typedef const __attribute__((address_space(1))) void gvoid_t;
typedef __attribute__((address_space(3))) void lvoid_t;
__device__ __forceinline__ void gl_lds16(const void* g, void* l) {
  __builtin_amdgcn_global_load_lds((gvoid_t*)g, (lvoid_t*)l, 16, 0, 0);
}

// ---------------------------------------------------------------------------
// x (fp32) -> bf16. 8M elements, 4096 blocks x 256 thr x 8.
// ---------------------------------------------------------------------------
__global__ void cvt_x_k(const float* __restrict__ in, u16* __restrict__ out) {
  int i = (blockIdx.x * 256 + threadIdx.x) * 8;
  float4 a = *(const float4*)(in + i);
  float4 b = *(const float4*)(in + i + 4);
  u16x8 o;
  o[0] = f2bf(a.x); o[1] = f2bf(a.y); o[2] = f2bf(a.z); o[3] = f2bf(a.w);
  o[4] = f2bf(b.x); o[5] = f2bf(b.y); o[6] = f2bf(b.z); o[7] = f2bf(b.w);
  *(u16x8*)(out + i) = o;
}

// ---------------------------------------------------------------------------
// Weight transpose fp32 -> bf16: out[c*R + r] = bf16(in[r*C + c])
// ---------------------------------------------------------------------------
__global__ void transpose_cvt_k(const float* __restrict__ in, u16* __restrict__ out,
                                int R, int C) {
  __shared__ float tile[32][33];
  int c0 = blockIdx.x * 32, r0 = blockIdx.y * 32;
  for (int i = threadIdx.y; i < 32; i += 8)
    tile[i][threadIdx.x] = in[(size_t)(r0 + i) * C + c0 + threadIdx.x];
  __syncthreads();
  for (int i = threadIdx.y; i < 32; i += 8)
    out[(size_t)(c0 + i) * R + r0 + threadIdx.x] = f2bf(tile[threadIdx.x][i]);
}

// ---------------------------------------------------------------------------
// ids -> float key mask (0.0 keep / -1e30 pad); per-block int64 detection.
// ---------------------------------------------------------------------------
__global__ void prep_mask_k(const int* __restrict__ in, float* __restrict__ maskf) {
  __shared__ int is64_s;
  if (threadIdx.x == 0) {
    int all0 = 1;
    for (int i = 1; i < 256; i += 2) all0 &= (in[i] == 0);
    is64_s = all0;
  }
  __syncthreads();
  int i = blockIdx.x * 256 + threadIdx.x;
  int v = is64_s ? in[2 * i] : in[i];
  maskf[i] = (v != 0) ? 0.f : -1e30f;
}

// ---------------------------------------------------------------------------
// m97-style GEMM mainloop: C[128,128] += A[m0:.,:K] * Bt[n0:.,:K]^T  (bf16)
// ---------------------------------------------------------------------------
__device__ __forceinline__ void gemm_mainloop(const u16* __restrict__ A,
                                              const u16* __restrict__ Bt,
                                              int K, int m0, int n0,
                                              u16* lds, f32x4 acc[4][4]) {
  const int tid = threadIdx.x;
  const int lane = tid & 63;
  const int w = tid >> 6;
  const int wm = (w >> 1) * 64, wn = (w & 1) * 64;
  const int quad = lane >> 4, ln = lane & 15;

  const int e0 = w * 512 + lane * 8;      // wave-uniform base + lane*16B
  const int r0 = e0 >> 5, c0 = e0 & 31;

  const u16* gA0 = A + (size_t)(m0 + r0) * K + c0;
  const u16* gA1 = gA0 + (size_t)64 * K;
  const u16* gB0 = Bt + (size_t)(n0 + r0) * K + c0;
  const u16* gB1 = gB0 + (size_t)64 * K;
  u16* lA0 = lds + e0;
  u16* lA1 = lds + e0 + 2048;
  u16* lB0 = lds + e0 + 4096;
  u16* lB1 = lds + e0 + 6144;

  for (int k0 = 0; k0 < K; k0 += 32) {
    gl_lds16(gA0 + k0, lA0);
    gl_lds16(gA1 + k0, lA1);
    gl_lds16(gB0 + k0, lB0);
    gl_lds16(gB1 + k0, lB1);
    __syncthreads();
    bf16x8 af[4], bfr[4];
#pragma unroll
    for (int mt = 0; mt < 4; mt++)
      af[mt] = *(const bf16x8*)(lds + (wm + mt * 16 + ln) * 32 + quad * 8);
#pragma unroll
    for (int nt = 0; nt < 4; nt++)
      bfr[nt] = *(const bf16x8*)(lds + 4096 + (wn + nt * 16 + ln) * 32 + quad * 8);
#pragma unroll
    for (int mt = 0; mt < 4; mt++)
#pragma unroll
      for (int nt = 0; nt < 4; nt++)
        acc[mt][nt] = __builtin_amdgcn_mfma_f32_16x16x32_bf16(af[mt], bfr[nt],
                                                              acc[mt][nt], 0, 0, 0);
    __syncthreads();
  }
}

// ---------------------------------------------------------------------------
// GEMM 1: qkv = X @ Wqkv. Q (pre-scaled log2e/8) and K scatter directly;
// V-blocks stage the C-tile in LDS and write Vt[B,H,D,T] rows COALESCED.
// Ct stride 130 u16 (dword-stride 65 == 1 mod 32): column reads conflict-free.
// ---------------------------------------------------------------------------
__global__ __launch_bounds__(256, 3)
void gemm_qkv_kernel(const u16* __restrict__ X, const u16* __restrict__ Wt,
                     u16* __restrict__ Qo, u16* __restrict__ Ko,
                     u16* __restrict__ Vto) {
  __shared__ __align__(16) u16 lds[128 * 130];
  const int m0 = blockIdx.y * 128, n0 = blockIdx.x * 128;
  f32x4 acc[4][4];
#pragma unroll
  for (int i = 0; i < 4; i++)
#pragma unroll
    for (int j = 0; j < 4; j++) acc[i][j] = (f32x4){0.f, 0.f, 0.f, 0.f};

  gemm_mainloop(X, Wt, En, m0, n0, lds, acc);

  const int tid = threadIdx.x, lane = tid & 63, w = tid >> 6;
  const int wm = (w >> 1) * 64, wn = (w & 1) * 64;
  const int quad = lane >> 4, ln = lane & 15;
  const int which = n0 >> 10;  // block-uniform: 0=Q 1=K 2=V
  const int bb = m0 >> 11, t0 = m0 & (Tn - 1);

  if (which < 2) {
#pragma unroll
    for (int mt = 0; mt < 4; mt++)
#pragma unroll
      for (int nt = 0; nt < 4; nt++)
#pragma unroll
        for (int r = 0; r < 4; r++) {
          int t = t0 + wm + mt * 16 + quad * 4 + r;   // C row = quad*4+reg
          int ng = n0 + wn + nt * 16 + ln;            // C col = lane&15
          int e = ng & (En - 1);
          int h = e >> 6, d = e & 63;
          size_t bh = (size_t)(bb * Hn + h);
          if (which == 0)
            Qo[(bh * Tn + t) * Dh + d] = f2bf(acc[mt][nt][r] * SCALE_Q);
          else
            Ko[(bh * Tn + t) * Dh + d] = f2bf(acc[mt][nt][r]);
        }
  } else {
    // stage C-tile -> LDS [128 rows(t)][130 stride, 128 cols(e)]
#pragma unroll
    for (int mt = 0; mt < 4; mt++)
#pragma unroll
      for (int nt = 0; nt < 4; nt++)
#pragma unroll
        for (int r = 0; r < 4; r++)
          lds[(wm + mt * 16 + quad * 4 + r) * 130 + wn + nt * 16 + ln] =
              f2bf(acc[mt][nt][r]);
    __syncthreads();
    const int ebase = n0 & (En - 1);
    // each wave writes 32 d-rows of Vt; lane covers t = lane and lane+64
#pragma unroll
    for (int i = 0; i < 32; i++) {
      int col = w * 32 + i;
      int e = ebase + col;
      int hh = e >> 6, d = e & 63;
      size_t vrow = (((size_t)(bb * Hn + hh)) * Dh + d) * Tn + t0;
      Vto[vrow + lane] = lds[lane * 130 + col];
      Vto[vrow + 64 + lane] = lds[(64 + lane) * 130 + col];
    }
  }
}

// ---------------------------------------------------------------------------
// GEMM 2: out = Y @ Wout + bias  -> fp32 output.
// ---------------------------------------------------------------------------
__global__ __launch_bounds__(256, 3)
void gemm_out_kernel(const u16* __restrict__ Y, const u16* __restrict__ Wt,
                     const float* __restrict__ bias, float* __restrict__ Out) {
  __shared__ __align__(16) u16 lds[8192];
  const int m0 = blockIdx.y * 128, n0 = blockIdx.x * 128;
  f32x4 acc[4][4];
#pragma unroll
  for (int i = 0; i < 4; i++)
#pragma unroll
    for (int j = 0; j < 4; j++) acc[i][j] = (f32x4){0.f, 0.f, 0.f, 0.f};

  gemm_mainloop(Y, Wt, En, m0, n0, lds, acc);

  const int tid = threadIdx.x, lane = tid & 63, w = tid >> 6;
  const int wm = (w >> 1) * 64, wn = (w & 1) * 64;
  const int quad = lane >> 4, ln = lane & 15;

#pragma unroll
  for (int mt = 0; mt < 4; mt++)
#pragma unroll
    for (int nt = 0; nt < 4; nt++)
#pragma unroll
      for (int r = 0; r < 4; r++) {
        int mg = m0 + wm + mt * 16 + quad * 4 + r;
        int ng = n0 + wn + nt * 16 + ln;
        Out[(size_t)mg * En + ng] = acc[mt][nt][r] + bias[ng];
      }
}

// ---------------------------------------------------------------------------
// Flash attention, R14: halved wave grain for 2x TLP.
// Grid 2048 (was 1024): q-tile 64 rows/block, 16 rows/wave. Per-wave state
// halves (aq[2], s[4], O[4], lsum[4]) -> VGPR well under the 85 cap of
// launch_bounds(256,6); LDS 9.7KB/block -> up to 8 blocks/CU resident
// (was grid-capped at 4). All 4 waves have identical tile counts
// (nfull = qt2 since w*16 < 64).
// CU-balanced qt2 map for 8 resident groups: g=bid>>8, s=(bid>>6)&3,
// qt2 = g even ? 31-4*(g>>1)-s : 4*(g>>1)+s — each CU's 8 blocks sum to
// 124 tiles for every s; full (qt2,bh) coverage.
// Pad-mask folded into QK MFMA C-in (R13). Barrier-free; P round-trip in
// LDS stride 76; pre-scaled Q -> exp2. setprio around MFMA clusters.
// ---------------------------------------------------------------------------
__global__ __launch_bounds__(256, 6)
void attn_kernel(const u16* __restrict__ Q, const u16* __restrict__ K,
                 const u16* __restrict__ Vt, const float* __restrict__ maskf,
                 u16* __restrict__ Y) {
  __shared__ __align__(16) u16 Pl[64 * 76];

  const int bid = blockIdx.x;
  const int g = bid >> 8, sq = (bid >> 6) & 3;
  const int qt2 = (g & 1) ? (4 * (g >> 1) + sq) : (31 - 4 * (g >> 1) - sq);
  const int bh = bid & 63;
  const int b = bh >> 4, h = bh & 15;
  const int tid = threadIdx.x, lane = tid & 63, w = tid >> 6;
  const int quad = lane >> 4, ln = lane & 15;
  const int qb = w * 16;
  const int g0 = qt2 * 64 + qb;       // first q row of this wave (16 rows)

  const size_t baseQK = (size_t)bh * (Tn * Dh);
  const size_t baseV = (size_t)bh * (Dh * Tn);
  const float* mrow = maskf + b * Tn;

  // Q fragments (pre-scaled) in registers for the whole kernel
  bf16x8 aq[2];
#pragma unroll
  for (int ks = 0; ks < 2; ks++)
    aq[ks] = *(const bf16x8*)(Q + baseQK +
        (size_t)(g0 + ln) * Dh + ks * 32 + quad * 8);

  f32x4 O[4];
  float lsum[4];
#pragma unroll
  for (int dt = 0; dt < 4; dt++) O[dt] = (f32x4){0.f, 0.f, 0.f, 0.f};
#pragma unroll
  for (int r = 0; r < 4; r++) lsum[r] = 0.f;

  auto tile = [&](int k0, bool dg) {
    // ---- phase 1: K fragments + QK^T (mask pre-loaded into C-in) ----
    f32x4 s[4];
    {
      bf16x8 bk[4][2];
      float kvf[4];
#pragma unroll
      for (int ct = 0; ct < 4; ct++) {
        kvf[ct] = mrow[k0 + ct * 16 + ln];
#pragma unroll
        for (int ks = 0; ks < 2; ks++)
          bk[ct][ks] = *(const bf16x8*)(K + baseQK +
              (size_t)(k0 + ct * 16 + ln) * Dh + ks * 32 + quad * 8);
      }
#pragma unroll
      for (int ct = 0; ct < 4; ct++)
        s[ct] = (f32x4){kvf[ct], kvf[ct], kvf[ct], kvf[ct]};
      __builtin_amdgcn_s_setprio(1);
#pragma unroll
      for (int ks = 0; ks < 2; ks++)
#pragma unroll
        for (int ct = 0; ct < 4; ct++)
          s[ct] = __builtin_amdgcn_mfma_f32_16x16x32_bf16(aq[ks], bk[ct][ks],
                                                          s[ct], 0, 0, 0);
      __builtin_amdgcn_s_setprio(0);
    }  // bk dead here

    // ---- phase 2: V fragments issued, latency hidden behind exp ----
    bf16x8 bv[4][2];
#pragma unroll
    for (int dt = 0; dt < 4; dt++)
#pragma unroll
      for (int ks = 0; ks < 2; ks++)
        bv[dt][ks] = *(const bf16x8*)(Vt + baseV +
            (size_t)(dt * 16 + ln) * Tn + k0 + ks * 32 + quad * 8);

    if (dg) {
#pragma unroll
      for (int ct = 0; ct < 4; ct++)
#pragma unroll
        for (int r = 0; r < 4; r++) {
          int qg = g0 + quad * 4 + r;
          int kg = k0 + ct * 16 + ln;
          float v = (kg > qg) ? -1e30f : s[ct][r];
          float p = exp2f(fminf(v, 126.f));
          lsum[r] += p;
          Pl[(qb + quad * 4 + r) * 76 + ct * 16 + ln] = f2bf(p);
        }
    } else {
#pragma unroll
      for (int ct = 0; ct < 4; ct++)
#pragma unroll
        for (int r = 0; r < 4; r++) {
          float p = exp2f(fminf(s[ct][r], 126.f));
          lsum[r] += p;
          Pl[(qb + quad * 4 + r) * 76 + ct * 16 + ln] = f2bf(p);
        }
    }

    // ---- phase 3: O += P V (wave-local LDS round-trip; no barrier) ----
    __builtin_amdgcn_s_setprio(1);
#pragma unroll
    for (int ks2 = 0; ks2 < 2; ks2++) {
      bf16x8 ap = *(const bf16x8*)(Pl + (qb + ln) * 76 + ks2 * 32 + quad * 8);
#pragma unroll
      for (int dt = 0; dt < 4; dt++)
        O[dt] = __builtin_amdgcn_mfma_f32_16x16x32_bf16(ap, bv[dt][ks2],
                                                        O[dt], 0, 0, 0);
    }
    __builtin_amdgcn_s_setprio(0);
  };

  const int nfull = qt2;              // fully-unmasked key tiles (qb<64)
  for (int kt = 0; kt < nfull; kt++) tile(kt * 64, false);
  tile(nfull * 64, true);             // exactly one diagonal tile

  // epilogue: reduce lsum across the 16 lanes of each quad-row, write Y
#pragma unroll
  for (int r = 0; r < 4; r++) {
    float l = lsum[r];
#pragma unroll
    for (int off = 1; off < 16; off <<= 1) l += __shfl_xor(l, off);
    float inv = 1.f / l;
    int tg = g0 + quad * 4 + r;
    size_t ob = ((size_t)b * Tn + tg) * En + h * Dh;
#pragma unroll
    for (int dt = 0; dt < 4; dt++)
      Y[ob + dt * 16 + ln] = f2bf(O[dt][r] * inv);
  }
}

// ---------------------------------------------------------------------------
// Workspace (u16 units), ~58.8 MB. Vt scratch lives in d_out (dead before
// gemm_out overwrites it — stream-ordered).
// ---------------------------------------------------------------------------
#define OFF_MASK  0                       // 8192 floats = 16384 u16
#define OFF_WQKVT 16384
#define OFF_WOUTT (OFF_WQKVT + 3145728)
#define OFF_Q     (OFF_WOUTT + 1048576)
#define OFF_K     (OFF_Q + 8388608)
#define OFF_XY    (OFF_K + 8388608)

extern "C" void kernel_launch(void* const* d_in, const int* in_sizes, int n_in,
                              void* d_out, int out_size, void* d_ws, size_t ws_size,
                              hipStream_t stream) {
  const float* x = nullptr;      // 8388608
  const int* ids_raw = nullptr;  // 8192
  const float* wqkv = nullptr;   // 3145728
  const float* wout = nullptr;   // 1048576
  const float* bias = nullptr;   // 1024
  for (int i = 0; i < n_in; i++) {
    switch (in_sizes[i]) {
      case 8388608: x = (const float*)d_in[i]; break;
      case 8192:    ids_raw = (const int*)d_in[i]; break;
      case 3145728: wqkv = (const float*)d_in[i]; break;
      case 1048576: wout = (const float*)d_in[i]; break;
      case 1024:    bias = (const float*)d_in[i]; break;
      default: break;
    }
  }
  if (!x) x = (const float*)d_in[0];
  if (!ids_raw) ids_raw = (const int*)d_in[1];
  if (!wqkv) wqkv = (const float*)d_in[2];
  if (!wout) wout = (const float*)d_in[3];
  if (!bias) bias = (const float*)d_in[4];

  u16* ws = (u16*)d_ws;
  float* maskf = (float*)(ws + OFF_MASK);
  u16* wqkv_t = ws + OFF_WQKVT;
  u16* wout_t = ws + OFF_WOUTT;
  u16* Qb = ws + OFF_Q;
  u16* Kb = ws + OFF_K;
  u16* XbYb = ws + OFF_XY;      // Xb (bf16 x), later reused as Yb
  u16* Vtb = (u16*)d_out;       // V^T scratch inside fp32 d_out
  float* out = (float*)d_out;

  prep_mask_k<<<32, 256, 0, stream>>>(ids_raw, maskf);
  cvt_x_k<<<4096, 256, 0, stream>>>(x, XbYb);
  transpose_cvt_k<<<dim3(96, 32), dim3(32, 8), 0, stream>>>(wqkv, wqkv_t, 1024, 3072);
  transpose_cvt_k<<<dim3(32, 32), dim3(32, 8), 0, stream>>>(wout, wout_t, 1024, 1024);
  gemm_qkv_kernel<<<dim3(24, 64), 256, 0, stream>>>(XbYb, wqkv_t, Qb, Kb, Vtb);
  attn_kernel<<<2048, 256, 0, stream>>>(Qb, Kb, Vtb, maskf, XbYb);
  gemm_out_kernel<<<dim3(8, 64), 256, 0, stream>>>(XbYb, wout_t, bias, out);
}

// Round 6
// 288.257 us; speedup vs baseline: 1.9073x; 1.9073x over previous
//
#include <hip/hip_runtime.h>
#include <hip/hip_bf16.h>
#include <stdint.h>

// Problem constants
#define Hn 16
#define Tn 2048
#define En 1024
#define Dh 64

typedef __bf16 bf16x8 __attribute__((ext_vector_type(8)));
typedef float f32x4 __attribute__((ext_vector_type(4)));
typedef unsigned short u16;
typedef u16 u16x8 __attribute__((ext_vector_type(8)));

#define SCALE_Q 0.18033688f   // log2(e)/8 folded into Q at projection time

__device__ __forceinline__ u16 f2bf(float f) {
  union { float f; uint32_t u; } v; v.f = f;
  uint32_t r = v.u + 0x7fffu + ((v.u >> 16) & 1u);   // RNE
  return (u16)(r >> 16);
}

typedef const __attribute__((address_space(1))) void gvoid_t;
typedef __attribute__((address_space(3))) void lvoid_t;
__device__ __forceinline__ void gl_lds16(const void* g, void* l) {
  __builtin_amdgcn_global_load_lds((gvoid_t*)g, (lvoid_t*)l, 16, 0, 0);
}

// ---------------------------------------------------------------------------
// x (fp32) -> bf16. 8M elements, 4096 blocks x 256 thr x 8.
// ---------------------------------------------------------------------------
__global__ void cvt_x_k(const float* __restrict__ in, u16* __restrict__ out) {
  int i = (blockIdx.x * 256 + threadIdx.x) * 8;
  float4 a = *(const float4*)(in + i);
  float4 b = *(const float4*)(in + i + 4);
  u16x8 o;
  o[0] = f2bf(a.x); o[1] = f2bf(a.y); o[2] = f2bf(a.z); o[3] = f2bf(a.w);
  o[4] = f2bf(b.x); o[5] = f2bf(b.y); o[6] = f2bf(b.z); o[7] = f2bf(b.w);
  *(u16x8*)(out + i) = o;
}

// ---------------------------------------------------------------------------
// Weight transpose fp32 -> bf16: out[c*R + r] = bf16(in[r*C + c])
// ---------------------------------------------------------------------------
__global__ void transpose_cvt_k(const float* __restrict__ in, u16* __restrict__ out,
                                int R, int C) {
  __shared__ float tile[32][33];
  int c0 = blockIdx.x * 32, r0 = blockIdx.y * 32;
  for (int i = threadIdx.y; i < 32; i += 8)
    tile[i][threadIdx.x] = in[(size_t)(r0 + i) * C + c0 + threadIdx.x];
  __syncthreads();
  for (int i = threadIdx.y; i < 32; i += 8)
    out[(size_t)(c0 + i) * R + r0 + threadIdx.x] = f2bf(tile[threadIdx.x][i]);
}

// ---------------------------------------------------------------------------
// ids -> float key mask (0.0 keep / -1e30 pad); per-block int64 detection.
// ---------------------------------------------------------------------------
__global__ void prep_mask_k(const int* __restrict__ in, float* __restrict__ maskf) {
  __shared__ int is64_s;
  if (threadIdx.x == 0) {
    int all0 = 1;
    for (int i = 1; i < 256; i += 2) all0 &= (in[i] == 0);
    is64_s = all0;
  }
  __syncthreads();
  int i = blockIdx.x * 256 + threadIdx.x;
  int v = is64_s ? in[2 * i] : in[i];
  maskf[i] = (v != 0) ? 0.f : -1e30f;
}

// ---------------------------------------------------------------------------
// m97-style GEMM mainloop: C[128,128] += A[m0:.,:K] * Bt[n0:.,:K]^T  (bf16)
// ---------------------------------------------------------------------------
__device__ __forceinline__ void gemm_mainloop(const u16* __restrict__ A,
                                              const u16* __restrict__ Bt,
                                              int K, int m0, int n0,
                                              u16* lds, f32x4 acc[4][4]) {
  const int tid = threadIdx.x;
  const int lane = tid & 63;
  const int w = tid >> 6;
  const int wm = (w >> 1) * 64, wn = (w & 1) * 64;
  const int quad = lane >> 4, ln = lane & 15;

  const int e0 = w * 512 + lane * 8;      // wave-uniform base + lane*16B
  const int r0 = e0 >> 5, c0 = e0 & 31;

  const u16* gA0 = A + (size_t)(m0 + r0) * K + c0;
  const u16* gA1 = gA0 + (size_t)64 * K;
  const u16* gB0 = Bt + (size_t)(n0 + r0) * K + c0;
  const u16* gB1 = gB0 + (size_t)64 * K;
  u16* lA0 = lds + e0;
  u16* lA1 = lds + e0 + 2048;
  u16* lB0 = lds + e0 + 4096;
  u16* lB1 = lds + e0 + 6144;

  for (int k0 = 0; k0 < K; k0 += 32) {
    gl_lds16(gA0 + k0, lA0);
    gl_lds16(gA1 + k0, lA1);
    gl_lds16(gB0 + k0, lB0);
    gl_lds16(gB1 + k0, lB1);
    __syncthreads();
    bf16x8 af[4], bfr[4];
#pragma unroll
    for (int mt = 0; mt < 4; mt++)
      af[mt] = *(const bf16x8*)(lds + (wm + mt * 16 + ln) * 32 + quad * 8);
#pragma unroll
    for (int nt = 0; nt < 4; nt++)
      bfr[nt] = *(const bf16x8*)(lds + 4096 + (wn + nt * 16 + ln) * 32 + quad * 8);
#pragma unroll
    for (int mt = 0; mt < 4; mt++)
#pragma unroll
      for (int nt = 0; nt < 4; nt++)
        acc[mt][nt] = __builtin_amdgcn_mfma_f32_16x16x32_bf16(af[mt], bfr[nt],
                                                              acc[mt][nt], 0, 0, 0);
    __syncthreads();
  }
}

// ---------------------------------------------------------------------------
// GEMM 1: qkv = X @ Wqkv. Q (pre-scaled log2e/8) and K scatter directly;
// V-blocks stage the C-tile in LDS and write Vt[B,H,D,T] rows COALESCED.
// Ct stride 130 u16 (dword-stride 65 == 1 mod 32): column reads conflict-free.
// ---------------------------------------------------------------------------
__global__ __launch_bounds__(256, 3)
void gemm_qkv_kernel(const u16* __restrict__ X, const u16* __restrict__ Wt,
                     u16* __restrict__ Qo, u16* __restrict__ Ko,
                     u16* __restrict__ Vto) {
  __shared__ __align__(16) u16 lds[128 * 130];
  const int m0 = blockIdx.y * 128, n0 = blockIdx.x * 128;
  f32x4 acc[4][4];
#pragma unroll
  for (int i = 0; i < 4; i++)
#pragma unroll
    for (int j = 0; j < 4; j++) acc[i][j] = (f32x4){0.f, 0.f, 0.f, 0.f};

  gemm_mainloop(X, Wt, En, m0, n0, lds, acc);

  const int tid = threadIdx.x, lane = tid & 63, w = tid >> 6;
  const int wm = (w >> 1) * 64, wn = (w & 1) * 64;
  const int quad = lane >> 4, ln = lane & 15;
  const int which = n0 >> 10;  // block-uniform: 0=Q 1=K 2=V
  const int bb = m0 >> 11, t0 = m0 & (Tn - 1);

  if (which < 2) {
#pragma unroll
    for (int mt = 0; mt < 4; mt++)
#pragma unroll
      for (int nt = 0; nt < 4; nt++)
#pragma unroll
        for (int r = 0; r < 4; r++) {
          int t = t0 + wm + mt * 16 + quad * 4 + r;   // C row = quad*4+reg
          int ng = n0 + wn + nt * 16 + ln;            // C col = lane&15
          int e = ng & (En - 1);
          int h = e >> 6, d = e & 63;
          size_t bh = (size_t)(bb * Hn + h);
          if (which == 0)
            Qo[(bh * Tn + t) * Dh + d] = f2bf(acc[mt][nt][r] * SCALE_Q);
          else
            Ko[(bh * Tn + t) * Dh + d] = f2bf(acc[mt][nt][r]);
        }
  } else {
    // stage C-tile -> LDS [128 rows(t)][130 stride, 128 cols(e)]
#pragma unroll
    for (int mt = 0; mt < 4; mt++)
#pragma unroll
      for (int nt = 0; nt < 4; nt++)
#pragma unroll
        for (int r = 0; r < 4; r++)
          lds[(wm + mt * 16 + quad * 4 + r) * 130 + wn + nt * 16 + ln] =
              f2bf(acc[mt][nt][r]);
    __syncthreads();
    const int ebase = n0 & (En - 1);
    // each wave writes 32 d-rows of Vt; lane covers t = lane and lane+64
#pragma unroll
    for (int i = 0; i < 32; i++) {
      int col = w * 32 + i;
      int e = ebase + col;
      int hh = e >> 6, d = e & 63;
      size_t vrow = (((size_t)(bb * Hn + hh)) * Dh + d) * Tn + t0;
      Vto[vrow + lane] = lds[lane * 130 + col];
      Vto[vrow + 64 + lane] = lds[(64 + lane) * 130 + col];
    }
  }
}

// ---------------------------------------------------------------------------
// GEMM 2: out = Y @ Wout + bias  -> fp32 output.
// ---------------------------------------------------------------------------
__global__ __launch_bounds__(256, 3)
void gemm_out_kernel(const u16* __restrict__ Y, const u16* __restrict__ Wt,
                     const float* __restrict__ bias, float* __restrict__ Out) {
  __shared__ __align__(16) u16 lds[8192];
  const int m0 = blockIdx.y * 128, n0 = blockIdx.x * 128;
  f32x4 acc[4][4];
#pragma unroll
  for (int i = 0; i < 4; i++)
#pragma unroll
    for (int j = 0; j < 4; j++) acc[i][j] = (f32x4){0.f, 0.f, 0.f, 0.f};

  gemm_mainloop(Y, Wt, En, m0, n0, lds, acc);

  const int tid = threadIdx.x, lane = tid & 63, w = tid >> 6;
  const int wm = (w >> 1) * 64, wn = (w & 1) * 64;
  const int quad = lane >> 4, ln = lane & 15;

#pragma unroll
  for (int mt = 0; mt < 4; mt++)
#pragma unroll
    for (int nt = 0; nt < 4; nt++)
#pragma unroll
      for (int r = 0; r < 4; r++) {
        int mg = m0 + wm + mt * 16 + quad * 4 + r;
        int ng = n0 + wn + nt * 16 + ln;
        Out[(size_t)mg * En + ng] = acc[mt][nt][r] + bias[ng];
      }
}

// ---------------------------------------------------------------------------
// Flash attention, R15 = R13 base (138us: 32 q-rows/wave, grid 1024,
// balanced qt map, mask folded into MFMA C-in) + LDS-staged K double buffer.
//
// K prefetch via global_load_lds (ZERO VGPR cost — R5 proved the register
// axis is closed: budget ~= 256/waves_per_SIMD, 3 waves max at ~80 live).
// Per tile: one __syncthreads (implicit vmcnt(0) is free — staged loads had
// a full tile of lead time), issue next tile's stage, ds_read current.
// Swizzle per rule #21 (gl_lds writes linearly): LDS linear, global SOURCE
// pre-swizzled col ^= (row&7)*8, read applies same XOR -> 2-way residual
// bank aliasing only (free, m136). Wave staging span stays contiguous 1KB.
// Waves have nfull = 2qt or 2qt+1 -> uniform 2qt+2 iterations, wave-local
// full/diag/idle selection (barrier-legal).
// ---------------------------------------------------------------------------
__global__ __launch_bounds__(256, 3)
void attn_kernel(const u16* __restrict__ Q, const u16* __restrict__ K,
                 const u16* __restrict__ Vt, const float* __restrict__ maskf,
                 u16* __restrict__ Y) {
  __shared__ __align__(16) u16 Pl[128 * 76];
  __shared__ __align__(16) u16 KL[2 * 4096];   // 2 x 8KB K tiles (src-swizzled)

  const int bid = blockIdx.x;
  const int g = bid >> 8, sq = (bid >> 6) & 3;
  int qt;
  if (g == 0)      qt = 15 - sq;
  else if (g == 1) qt = sq;
  else if (g == 2) qt = 11 - sq;
  else             qt = 4 + sq;
  const int bh = bid & 63;
  const int b = bh >> 4, h = bh & 15;
  const int tid = threadIdx.x, lane = tid & 63, w = tid >> 6;
  const int quad = lane >> 4, ln = lane & 15;
  const int qb = w * 32;
  const int g0 = qt * 128 + qb;       // first q row of this wave

  const size_t baseQK = (size_t)bh * (Tn * Dh);
  const size_t baseV = (size_t)bh * (Dh * Tn);
  const float* mrow = maskf + b * Tn;
  const u16* Kp = K + baseQK;

  // staging addresses: thread covers rows srow and srow+32, swizzled col.
  // (srow+32)&7 == srow&7, so one scol serves both halves.
  const int srow = tid >> 3;
  const int scol = ((tid & 7) * 8) ^ ((srow & 7) * 8);
  const u16* gK0 = Kp + (size_t)srow * Dh + scol;
  const u16* gK1 = Kp + (size_t)(srow + 32) * Dh + scol;
  u16* lK0 = KL + tid * 8;
  u16* lK1 = lK0 + 2048;

  auto stage = [&](int buf, int k0) {
    gl_lds16(gK0 + (size_t)k0 * Dh, lK0 + buf * 4096);
    gl_lds16(gK1 + (size_t)k0 * Dh, lK1 + buf * 4096);
  };

  // Q fragments (pre-scaled) in registers for the whole kernel
  bf16x8 aq[2][2];
#pragma unroll
  for (int rt = 0; rt < 2; rt++)
#pragma unroll
    for (int ks = 0; ks < 2; ks++)
      aq[rt][ks] = *(const bf16x8*)(Q + baseQK +
          (size_t)(g0 + rt * 16 + ln) * Dh + ks * 32 + quad * 8);

  f32x4 O[2][4];
  float lsum[2][4];
#pragma unroll
  for (int rt = 0; rt < 2; rt++) {
#pragma unroll
    for (int dt = 0; dt < 4; dt++) O[rt][dt] = (f32x4){0.f, 0.f, 0.f, 0.f};
#pragma unroll
    for (int r = 0; r < 4; r++) lsum[rt][r] = 0.f;
  }

  auto tile = [&](const u16* kl, int k0, bool dg) {
    // ---- phase 1: K fragments from LDS + QK^T (mask in MFMA C-in) ----
    f32x4 s[2][4];
    {
      bf16x8 bk[4][2];
      float kvf[4];
#pragma unroll
      for (int ct = 0; ct < 4; ct++) {
        kvf[ct] = mrow[k0 + ct * 16 + ln];
#pragma unroll
        for (int ks = 0; ks < 2; ks++)
          bk[ct][ks] = *(const bf16x8*)(kl + (ct * 16 + ln) * 64 +
                                        ((ks * 32 + quad * 8) ^ ((ln & 7) * 8)));
      }
#pragma unroll
      for (int rt = 0; rt < 2; rt++)
#pragma unroll
        for (int ct = 0; ct < 4; ct++)
          s[rt][ct] = (f32x4){kvf[ct], kvf[ct], kvf[ct], kvf[ct]};
      __builtin_amdgcn_s_setprio(1);
#pragma unroll
      for (int ks = 0; ks < 2; ks++)
#pragma unroll
        for (int rt = 0; rt < 2; rt++)
#pragma unroll
          for (int ct = 0; ct < 4; ct++)
            s[rt][ct] = __builtin_amdgcn_mfma_f32_16x16x32_bf16(aq[rt][ks], bk[ct][ks],
                                                                s[rt][ct], 0, 0, 0);
      __builtin_amdgcn_s_setprio(0);
    }  // bk dead here

    // ---- phase 2: V fragments issued, latency hidden behind exp ----
    bf16x8 bv[4][2];
#pragma unroll
    for (int dt = 0; dt < 4; dt++)
#pragma unroll
      for (int ks = 0; ks < 2; ks++)
        bv[dt][ks] = *(const bf16x8*)(Vt + baseV +
            (size_t)(dt * 16 + ln) * Tn + k0 + ks * 32 + quad * 8);

#pragma unroll
    for (int rt = 0; rt < 2; rt++) {
      if (dg) {
#pragma unroll
        for (int ct = 0; ct < 4; ct++)
#pragma unroll
          for (int r = 0; r < 4; r++) {
            int qg = g0 + rt * 16 + quad * 4 + r;
            int kg = k0 + ct * 16 + ln;
            float v = (kg > qg) ? -1e30f : s[rt][ct][r];
            float p = exp2f(fminf(v, 126.f));
            lsum[rt][r] += p;
            Pl[(qb + rt * 16 + quad * 4 + r) * 76 + ct * 16 + ln] = f2bf(p);
          }
      } else {
#pragma unroll
        for (int ct = 0; ct < 4; ct++)
#pragma unroll
          for (int r = 0; r < 4; r++) {
            float p = exp2f(fminf(s[rt][ct][r], 126.f));
            lsum[rt][r] += p;
            Pl[(qb + rt * 16 + quad * 4 + r) * 76 + ct * 16 + ln] = f2bf(p);
          }
      }
    }

    // ---- phase 3: O += P V (wave-local LDS round-trip; no barrier) ----
    __builtin_amdgcn_s_setprio(1);
#pragma unroll
    for (int ks2 = 0; ks2 < 2; ks2++)
#pragma unroll
      for (int rt = 0; rt < 2; rt++) {
        bf16x8 ap = *(const bf16x8*)(Pl + (qb + rt * 16 + ln) * 76 + ks2 * 32 + quad * 8);
#pragma unroll
        for (int dt = 0; dt < 4; dt++)
          O[rt][dt] = __builtin_amdgcn_mfma_f32_16x16x32_bf16(ap, bv[dt][ks2],
                                                              O[rt][dt], 0, 0, 0);
      }
    __builtin_amdgcn_s_setprio(0);
  };

  const int nfull = g0 >> 6;          // per-wave: 2qt (w<2) or 2qt+1 (w>=2)
  const int NT = 2 * qt + 1;          // uniform last iteration index
  stage(0, 0);
  int cur = 0;
  for (int kt = 0; kt <= NT; kt++) {
    __syncthreads();                  // staged K(kt) ready; buf[cur^1] free
    if (kt < NT) stage(cur ^ 1, (kt + 1) * 64);
    if (kt < nfull)       tile(KL + cur * 4096, kt * 64, false);
    else if (kt == nfull) tile(KL + cur * 4096, kt * 64, true);
    // else: waves 0,1 idle on the final iteration (barrier-participating)
    cur ^= 1;
  }

  // epilogue: reduce lsum across the 16 lanes of each quad-row, write Y
#pragma unroll
  for (int rt = 0; rt < 2; rt++)
#pragma unroll
    for (int r = 0; r < 4; r++) {
      float l = lsum[rt][r];
#pragma unroll
      for (int off = 1; off < 16; off <<= 1) l += __shfl_xor(l, off);
      float inv = 1.f / l;
      int tg = g0 + rt * 16 + quad * 4 + r;
      size_t ob = ((size_t)b * Tn + tg) * En + h * Dh;
#pragma unroll
      for (int dt = 0; dt < 4; dt++)
        Y[ob + dt * 16 + ln] = f2bf(O[rt][dt][r] * inv);
    }
}

// ---------------------------------------------------------------------------
// Workspace (u16 units), ~58.8 MB. Vt scratch lives in d_out (dead before
// gemm_out overwrites it — stream-ordered).
// ---------------------------------------------------------------------------
#define OFF_MASK  0                       // 8192 floats = 16384 u16
#define OFF_WQKVT 16384
#define OFF_WOUTT (OFF_WQKVT + 3145728)
#define OFF_Q     (OFF_WOUTT + 1048576)
#define OFF_K     (OFF_Q + 8388608)
#define OFF_XY    (OFF_K + 8388608)

extern "C" void kernel_launch(void* const* d_in, const int* in_sizes, int n_in,
                              void* d_out, int out_size, void* d_ws, size_t ws_size,
                              hipStream_t stream) {
  const float* x = nullptr;      // 8388608
  const int* ids_raw = nullptr;  // 8192
  const float* wqkv = nullptr;   // 3145728
  const float* wout = nullptr;   // 1048576
  const float* bias = nullptr;   // 1024
  for (int i = 0; i < n_in; i++) {
    switch (in_sizes[i]) {
      case 8388608: x = (const float*)d_in[i]; break;
      case 8192:    ids_raw = (const int*)d_in[i]; break;
      case 3145728: wqkv = (const float*)d_in[i]; break;
      case 1048576: wout = (const float*)d_in[i]; break;
      case 1024:    bias = (const float*)d_in[i]; break;
      default: break;
    }
  }
  if (!x) x = (const float*)d_in[0];
  if (!ids_raw) ids_raw = (const int*)d_in[1];
  if (!wqkv) wqkv = (const float*)d_in[2];
  if (!wout) wout = (const float*)d_in[3];
  if (!bias) bias = (const float*)d_in[4];

  u16* ws = (u16*)d_ws;
  float* maskf = (float*)(ws + OFF_MASK);
  u16* wqkv_t = ws + OFF_WQKVT;
  u16* wout_t = ws + OFF_WOUTT;
  u16* Qb = ws + OFF_Q;
  u16* Kb = ws + OFF_K;
  u16* XbYb = ws + OFF_XY;      // Xb (bf16 x), later reused as Yb
  u16* Vtb = (u16*)d_out;       // V^T scratch inside fp32 d_out
  float* out = (float*)d_out;

  prep_mask_k<<<32, 256, 0, stream>>>(ids_raw, maskf);
  cvt_x_k<<<4096, 256, 0, stream>>>(x, XbYb);
  transpose_cvt_k<<<dim3(96, 32), dim3(32, 8), 0, stream>>>(wqkv, wqkv_t, 1024, 3072);
  transpose_cvt_k<<<dim3(32, 32), dim3(32, 8), 0, stream>>>(wout, wout_t, 1024, 1024);
  gemm_qkv_kernel<<<dim3(24, 64), 256, 0, stream>>>(XbYb, wqkv_t, Qb, Kb, Vtb);
  attn_kernel<<<1024, 256, 0, stream>>>(Qb, Kb, Vtb, maskf, XbYb);
  gemm_out_kernel<<<dim3(8, 64), 256, 0, stream>>>(XbYb, wout_t, bias, out);
}

// Round 8
// 283.701 us; speedup vs baseline: 1.9379x; 1.0161x over previous
//
#include <hip/hip_runtime.h>
#include <hip/hip_bf16.h>
#include <stdint.h>

// Problem constants
#define Hn 16
#define Tn 2048
#define En 1024
#define Dh 64

typedef __bf16 bf16x8 __attribute__((ext_vector_type(8)));
typedef float f32x4 __attribute__((ext_vector_type(4)));
typedef unsigned short u16;
typedef u16 u16x8 __attribute__((ext_vector_type(8)));

#define SCALE_Q 0.18033688f   // log2(e)/8 folded into Q at projection time

// R16: hardware RNE convert (v_cvt_pk_bf16_f32 class) replaces 4-op manual
// bit-twiddle. Same rounding mode -> bit-identical on normals.
__device__ __forceinline__ u16 f2bf(float f) {
  __bf16 b = (__bf16)f;
  return __builtin_bit_cast(u16, b);
}

typedef const __attribute__((address_space(1))) void gvoid_t;
typedef __attribute__((address_space(3))) void lvoid_t;
__device__ __forceinline__ void gl_lds16(const void* g, void* l) {
  __builtin_amdgcn_global_load_lds((gvoid_t*)g, (lvoid_t*)l, 16, 0, 0);
}

// ---------------------------------------------------------------------------
// x (fp32) -> bf16. 8M elements, 4096 blocks x 256 thr x 8.
// ---------------------------------------------------------------------------
__global__ void cvt_x_k(const float* __restrict__ in, u16* __restrict__ out) {
  int i = (blockIdx.x * 256 + threadIdx.x) * 8;
  float4 a = *(const float4*)(in + i);
  float4 b = *(const float4*)(in + i + 4);
  u16x8 o;
  o[0] = f2bf(a.x); o[1] = f2bf(a.y); o[2] = f2bf(a.z); o[3] = f2bf(a.w);
  o[4] = f2bf(b.x); o[5] = f2bf(b.y); o[6] = f2bf(b.z); o[7] = f2bf(b.w);
  *(u16x8*)(out + i) = o;
}

// ---------------------------------------------------------------------------
// Weight transpose fp32 -> bf16: out[c*R + r] = bf16(in[r*C + c])
// ---------------------------------------------------------------------------
__global__ void transpose_cvt_k(const float* __restrict__ in, u16* __restrict__ out,
                                int R, int C) {
  __shared__ float tile[32][33];
  int c0 = blockIdx.x * 32, r0 = blockIdx.y * 32;
  for (int i = threadIdx.y; i < 32; i += 8)
    tile[i][threadIdx.x] = in[(size_t)(r0 + i) * C + c0 + threadIdx.x];
  __syncthreads();
  for (int i = threadIdx.y; i < 32; i += 8)
    out[(size_t)(c0 + i) * R + r0 + threadIdx.x] = f2bf(tile[threadIdx.x][i]);
}

// ---------------------------------------------------------------------------
// ids -> float key mask (0.0 keep / -1e30 pad); per-block int64 detection.
// ---------------------------------------------------------------------------
__global__ void prep_mask_k(const int* __restrict__ in, float* __restrict__ maskf) {
  __shared__ int is64_s;
  if (threadIdx.x == 0) {
    int all0 = 1;
    for (int i = 1; i < 256; i += 2) all0 &= (in[i] == 0);
    is64_s = all0;
  }
  __syncthreads();
  int i = blockIdx.x * 256 + threadIdx.x;
  int v = is64_s ? in[2 * i] : in[i];
  maskf[i] = (v != 0) ? 0.f : -1e30f;
}

// ---------------------------------------------------------------------------
// R16 GEMM mainloop: BK=64 (halved barriers: 2 per 64-K vs 2 per 32-K) with
// rule-#21 XOR swizzle. Old layout: [row][32] fragment reads were 8-way
// bank-conflicted (row stride 64B; m98 measured 1.7e7 conflicts on the m97
// structure). New: LDS linear [128][64], global SOURCE col ^= (row&7)*8,
// read applies same XOR -> 8 rows spread over all 32 banks, residual 2-way
// aliasing only (free, m136). Compute split into two kk-halves to keep the
// fragment live-set at 32 VGPRs (VGPR ~164 preserved; no spill).
// C[128,128] += A[m0:.,:K] * Bt[n0:.,:K]^T  (bf16)
// ---------------------------------------------------------------------------
__device__ __forceinline__ void gemm_mainloop(const u16* __restrict__ A,
                                              const u16* __restrict__ Bt,
                                              int K, int m0, int n0,
                                              u16* lds, f32x4 acc[4][4]) {
  const int tid = threadIdx.x;
  const int lane = tid & 63;
  const int w = tid >> 6;
  const int wm = (w >> 1) * 64, wn = (w & 1) * 64;
  const int quad = lane >> 4, ln = lane & 15;

  const int e0 = w * 512 + lane * 8;          // 0..2047; wave-uniform + lane*16B
  const int r0 = e0 >> 6;                     // source row 0..31 within chunk
  const int cS = (e0 & 63) ^ ((r0 & 7) * 8);  // pre-swizzled source col

  const u16* gA = A + (size_t)(m0 + r0) * K + cS;
  const u16* gB = Bt + (size_t)(n0 + r0) * K + cS;
  u16* lA = lds + e0;
  u16* lB = lds + 8192 + e0;
  const int xA = (ln & 7) * 8;                // read-side XOR ((row&7)*8)

  for (int k0 = 0; k0 < K; k0 += 64) {
#pragma unroll
    for (int c = 0; c < 4; c++) {             // 4 row-chunks of 32 for A and B
      gl_lds16(gA + (size_t)(c * 32) * K + k0, lA + c * 2048);
      gl_lds16(gB + (size_t)(c * 32) * K + k0, lB + c * 2048);
    }
    __syncthreads();
#pragma unroll
    for (int kk = 0; kk < 2; kk++) {
      bf16x8 af[4], bfr[4];
#pragma unroll
      for (int mt = 0; mt < 4; mt++)
        af[mt] = *(const bf16x8*)(lds + (wm + mt * 16 + ln) * 64 +
                                  ((kk * 32 + quad * 8) ^ xA));
#pragma unroll
      for (int nt = 0; nt < 4; nt++)
        bfr[nt] = *(const bf16x8*)(lds + 8192 + (wn + nt * 16 + ln) * 64 +
                                   ((kk * 32 + quad * 8) ^ xA));
#pragma unroll
      for (int mt = 0; mt < 4; mt++)
#pragma unroll
        for (int nt = 0; nt < 4; nt++)
          acc[mt][nt] = __builtin_amdgcn_mfma_f32_16x16x32_bf16(af[mt], bfr[nt],
                                                                acc[mt][nt], 0, 0, 0);
    }
    __syncthreads();
  }
}

// ---------------------------------------------------------------------------
// GEMM 1: qkv = X @ Wqkv. Q (pre-scaled log2e/8) and K scatter directly;
// V-blocks stage the C-tile in LDS and write Vt[B,H,D,T] rows COALESCED.
// Ct stride 130 u16 (dword-stride 65 == 1 mod 32): column reads conflict-free.
// ---------------------------------------------------------------------------
__global__ __launch_bounds__(256, 3)
void gemm_qkv_kernel(const u16* __restrict__ X, const u16* __restrict__ Wt,
                     u16* __restrict__ Qo, u16* __restrict__ Ko,
                     u16* __restrict__ Vto) {
  __shared__ __align__(16) u16 lds[128 * 130];   // staging 16384 + epilogue 16640
  const int m0 = blockIdx.y * 128, n0 = blockIdx.x * 128;
  f32x4 acc[4][4];
#pragma unroll
  for (int i = 0; i < 4; i++)
#pragma unroll
    for (int j = 0; j < 4; j++) acc[i][j] = (f32x4){0.f, 0.f, 0.f, 0.f};

  gemm_mainloop(X, Wt, En, m0, n0, lds, acc);

  const int tid = threadIdx.x, lane = tid & 63, w = tid >> 6;
  const int wm = (w >> 1) * 64, wn = (w & 1) * 64;
  const int quad = lane >> 4, ln = lane & 15;
  const int which = n0 >> 10;  // block-uniform: 0=Q 1=K 2=V
  const int bb = m0 >> 11, t0 = m0 & (Tn - 1);

  if (which < 2) {
#pragma unroll
    for (int mt = 0; mt < 4; mt++)
#pragma unroll
      for (int nt = 0; nt < 4; nt++)
#pragma unroll
        for (int r = 0; r < 4; r++) {
          int t = t0 + wm + mt * 16 + quad * 4 + r;   // C row = quad*4+reg
          int ng = n0 + wn + nt * 16 + ln;            // C col = lane&15
          int e = ng & (En - 1);
          int h = e >> 6, d = e & 63;
          size_t bh = (size_t)(bb * Hn + h);
          if (which == 0)
            Qo[(bh * Tn + t) * Dh + d] = f2bf(acc[mt][nt][r] * SCALE_Q);
          else
            Ko[(bh * Tn + t) * Dh + d] = f2bf(acc[mt][nt][r]);
        }
  } else {
    // stage C-tile -> LDS [128 rows(t)][130 stride, 128 cols(e)]
#pragma unroll
    for (int mt = 0; mt < 4; mt++)
#pragma unroll
      for (int nt = 0; nt < 4; nt++)
#pragma unroll
        for (int r = 0; r < 4; r++)
          lds[(wm + mt * 16 + quad * 4 + r) * 130 + wn + nt * 16 + ln] =
              f2bf(acc[mt][nt][r]);
    __syncthreads();
    const int ebase = n0 & (En - 1);
    // each wave writes 32 d-rows of Vt; lane covers t = lane and lane+64
#pragma unroll
    for (int i = 0; i < 32; i++) {
      int col = w * 32 + i;
      int e = ebase + col;
      int hh = e >> 6, d = e & 63;
      size_t vrow = (((size_t)(bb * Hn + hh)) * Dh + d) * Tn + t0;
      Vto[vrow + lane] = lds[lane * 130 + col];
      Vto[vrow + 64 + lane] = lds[(64 + lane) * 130 + col];
    }
  }
}

// ---------------------------------------------------------------------------
// GEMM 2: out = Y @ Wout + bias  -> fp32 output.
// ---------------------------------------------------------------------------
__global__ __launch_bounds__(256, 3)
void gemm_out_kernel(const u16* __restrict__ Y, const u16* __restrict__ Wt,
                     const float* __restrict__ bias, float* __restrict__ Out) {
  __shared__ __align__(16) u16 lds[16384];
  const int m0 = blockIdx.y * 128, n0 = blockIdx.x * 128;
  f32x4 acc[4][4];
#pragma unroll
  for (int i = 0; i < 4; i++)
#pragma unroll
    for (int j = 0; j < 4; j++) acc[i][j] = (f32x4){0.f, 0.f, 0.f, 0.f};

  gemm_mainloop(Y, Wt, En, m0, n0, lds, acc);

  const int tid = threadIdx.x, lane = tid & 63, w = tid >> 6;
  const int wm = (w >> 1) * 64, wn = (w & 1) * 64;
  const int quad = lane >> 4, ln = lane & 15;

#pragma unroll
  for (int mt = 0; mt < 4; mt++)
#pragma unroll
    for (int nt = 0; nt < 4; nt++)
#pragma unroll
      for (int r = 0; r < 4; r++) {
        int mg = m0 + wm + mt * 16 + quad * 4 + r;
        int ng = n0 + wn + nt * 16 + ln;
        Out[(size_t)mg * En + ng] = acc[mt][nt][r] + bias[ng];
      }
}

// ---------------------------------------------------------------------------
// Flash attention, R15 structure (99us): 32 q-rows/wave, grid 1024, balanced
// qt map, mask folded into MFMA C-in, LDS-staged K double buffer via
// global_load_lds (zero VGPR), source-swizzled per rule #21.
// R16 delta: f2bf hardware convert only. (V-staging deferred: +16KB LDS
// would drop 4->3 blocks/CU and break the 4-resident balance.)
// ---------------------------------------------------------------------------
__global__ __launch_bounds__(256, 3)
void attn_kernel(const u16* __restrict__ Q, const u16* __restrict__ K,
                 const u16* __restrict__ Vt, const float* __restrict__ maskf,
                 u16* __restrict__ Y) {
  __shared__ __align__(16) u16 Pl[128 * 76];
  __shared__ __align__(16) u16 KL[2 * 4096];   // 2 x 8KB K tiles (src-swizzled)

  const int bid = blockIdx.x;
  const int g = bid >> 8, sq = (bid >> 6) & 3;
  int qt;
  if (g == 0)      qt = 15 - sq;
  else if (g == 1) qt = sq;
  else if (g == 2) qt = 11 - sq;
  else             qt = 4 + sq;
  const int bh = bid & 63;
  const int b = bh >> 4, h = bh & 15;
  const int tid = threadIdx.x, lane = tid & 63, w = tid >> 6;
  const int quad = lane >> 4, ln = lane & 15;
  const int qb = w * 32;
  const int g0 = qt * 128 + qb;       // first q row of this wave

  const size_t baseQK = (size_t)bh * (Tn * Dh);
  const size_t baseV = (size_t)bh * (Dh * Tn);
  const float* mrow = maskf + b * Tn;
  const u16* Kp = K + baseQK;

  // staging addresses: thread covers rows srow and srow+32, swizzled col.
  // (srow+32)&7 == srow&7, so one scol serves both halves.
  const int srow = tid >> 3;
  const int scol = ((tid & 7) * 8) ^ ((srow & 7) * 8);
  const u16* gK0 = Kp + (size_t)srow * Dh + scol;
  const u16* gK1 = Kp + (size_t)(srow + 32) * Dh + scol;
  u16* lK0 = KL + tid * 8;
  u16* lK1 = lK0 + 2048;

  auto stage = [&](int buf, int k0) {
    gl_lds16(gK0 + (size_t)k0 * Dh, lK0 + buf * 4096);
    gl_lds16(gK1 + (size_t)k0 * Dh, lK1 + buf * 4096);
  };

  // Q fragments (pre-scaled) in registers for the whole kernel
  bf16x8 aq[2][2];
#pragma unroll
  for (int rt = 0; rt < 2; rt++)
#pragma unroll
    for (int ks = 0; ks < 2; ks++)
      aq[rt][ks] = *(const bf16x8*)(Q + baseQK +
          (size_t)(g0 + rt * 16 + ln) * Dh + ks * 32 + quad * 8);

  f32x4 O[2][4];
  float lsum[2][4];
#pragma unroll
  for (int rt = 0; rt < 2; rt++) {
#pragma unroll
    for (int dt = 0; dt < 4; dt++) O[rt][dt] = (f32x4){0.f, 0.f, 0.f, 0.f};
#pragma unroll
    for (int r = 0; r < 4; r++) lsum[rt][r] = 0.f;
  }

  auto tile = [&](const u16* kl, int k0, bool dg) {
    // ---- phase 1: K fragments from LDS + QK^T (mask in MFMA C-in) ----
    f32x4 s[2][4];
    {
      bf16x8 bk[4][2];
      float kvf[4];
#pragma unroll
      for (int ct = 0; ct < 4; ct++) {
        kvf[ct] = mrow[k0 + ct * 16 + ln];
#pragma unroll
        for (int ks = 0; ks < 2; ks++)
          bk[ct][ks] = *(const bf16x8*)(kl + (ct * 16 + ln) * 64 +
                                        ((ks * 32 + quad * 8) ^ ((ln & 7) * 8)));
      }
#pragma unroll
      for (int rt = 0; rt < 2; rt++)
#pragma unroll
        for (int ct = 0; ct < 4; ct++)
          s[rt][ct] = (f32x4){kvf[ct], kvf[ct], kvf[ct], kvf[ct]};
      __builtin_amdgcn_s_setprio(1);
#pragma unroll
      for (int ks = 0; ks < 2; ks++)
#pragma unroll
        for (int rt = 0; rt < 2; rt++)
#pragma unroll
          for (int ct = 0; ct < 4; ct++)
            s[rt][ct] = __builtin_amdgcn_mfma_f32_16x16x32_bf16(aq[rt][ks], bk[ct][ks],
                                                                s[rt][ct], 0, 0, 0);
      __builtin_amdgcn_s_setprio(0);
    }  // bk dead here

    // ---- phase 2: V fragments issued, latency hidden behind exp ----
    bf16x8 bv[4][2];
#pragma unroll
    for (int dt = 0; dt < 4; dt++)
#pragma unroll
      for (int ks = 0; ks < 2; ks++)
        bv[dt][ks] = *(const bf16x8*)(Vt + baseV +
            (size_t)(dt * 16 + ln) * Tn + k0 + ks * 32 + quad * 8);

#pragma unroll
    for (int rt = 0; rt < 2; rt++) {
      if (dg) {
#pragma unroll
        for (int ct = 0; ct < 4; ct++)
#pragma unroll
          for (int r = 0; r < 4; r++) {
            int qg = g0 + rt * 16 + quad * 4 + r;
            int kg = k0 + ct * 16 + ln;
            float v = (kg > qg) ? -1e30f : s[rt][ct][r];
            float p = exp2f(fminf(v, 126.f));
            lsum[rt][r] += p;
            Pl[(qb + rt * 16 + quad * 4 + r) * 76 + ct * 16 + ln] = f2bf(p);
          }
      } else {
#pragma unroll
        for (int ct = 0; ct < 4; ct++)
#pragma unroll
          for (int r = 0; r < 4; r++) {
            float p = exp2f(fminf(s[rt][ct][r], 126.f));
            lsum[rt][r] += p;
            Pl[(qb + rt * 16 + quad * 4 + r) * 76 + ct * 16 + ln] = f2bf(p);
          }
      }
    }

    // ---- phase 3: O += P V (wave-local LDS round-trip; no barrier) ----
    __builtin_amdgcn_s_setprio(1);
#pragma unroll
    for (int ks2 = 0; ks2 < 2; ks2++)
#pragma unroll
      for (int rt = 0; rt < 2; rt++) {
        bf16x8 ap = *(const bf16x8*)(Pl + (qb + rt * 16 + ln) * 76 + ks2 * 32 + quad * 8);
#pragma unroll
        for (int dt = 0; dt < 4; dt++)
          O[rt][dt] = __builtin_amdgcn_mfma_f32_16x16x32_bf16(ap, bv[dt][ks2],
                                                              O[rt][dt], 0, 0, 0);
      }
    __builtin_amdgcn_s_setprio(0);
  };

  const int nfull = g0 >> 6;          // per-wave: 2qt (w<2) or 2qt+1 (w>=2)
  const int NT = 2 * qt + 1;          // uniform last iteration index
  stage(0, 0);
  int cur = 0;
  for (int kt = 0; kt <= NT; kt++) {
    __syncthreads();                  // staged K(kt) ready; buf[cur^1] free
    if (kt < NT) stage(cur ^ 1, (kt + 1) * 64);
    if (kt < nfull)       tile(KL + cur * 4096, kt * 64, false);
    else if (kt == nfull) tile(KL + cur * 4096, kt * 64, true);
    // else: waves 0,1 idle on the final iteration (barrier-participating)
    cur ^= 1;
  }

  // epilogue: reduce lsum across the 16 lanes of each quad-row, write Y
#pragma unroll
  for (int rt = 0; rt < 2; rt++)
#pragma unroll
    for (int r = 0; r < 4; r++) {
      float l = lsum[rt][r];
#pragma unroll
      for (int off = 1; off < 16; off <<= 1) l += __shfl_xor(l, off);
      float inv = 1.f / l;
      int tg = g0 + rt * 16 + quad * 4 + r;
      size_t ob = ((size_t)b * Tn + tg) * En + h * Dh;
#pragma unroll
      for (int dt = 0; dt < 4; dt++)
        Y[ob + dt * 16 + ln] = f2bf(O[rt][dt][r] * inv);
    }
}

// ---------------------------------------------------------------------------
// Workspace (u16 units), ~58.8 MB. Vt scratch lives in d_out (dead before
// gemm_out overwrites it — stream-ordered).
// ---------------------------------------------------------------------------
#define OFF_MASK  0                       // 8192 floats = 16384 u16
#define OFF_WQKVT 16384
#define OFF_WOUTT (OFF_WQKVT + 3145728)
#define OFF_Q     (OFF_WOUTT + 1048576)
#define OFF_K     (OFF_Q + 8388608)
#define OFF_XY    (OFF_K + 8388608)

extern "C" void kernel_launch(void* const* d_in, const int* in_sizes, int n_in,
                              void* d_out, int out_size, void* d_ws, size_t ws_size,
                              hipStream_t stream) {
  const float* x = nullptr;      // 8388608
  const int* ids_raw = nullptr;  // 8192
  const float* wqkv = nullptr;   // 3145728
  const float* wout = nullptr;   // 1048576
  const float* bias = nullptr;   // 1024
  for (int i = 0; i < n_in; i++) {
    switch (in_sizes[i]) {
      case 8388608: x = (const float*)d_in[i]; break;
      case 8192:    ids_raw = (const int*)d_in[i]; break;
      case 3145728: wqkv = (const float*)d_in[i]; break;
      case 1048576: wout = (const float*)d_in[i]; break;
      case 1024:    bias = (const float*)d_in[i]; break;
      default: break;
    }
  }
  if (!x) x = (const float*)d_in[0];
  if (!ids_raw) ids_raw = (const int*)d_in[1];
  if (!wqkv) wqkv = (const float*)d_in[2];
  if (!wout) wout = (const float*)d_in[3];
  if (!bias) bias = (const float*)d_in[4];

  u16* ws = (u16*)d_ws;
  float* maskf = (float*)(ws + OFF_MASK);
  u16* wqkv_t = ws + OFF_WQKVT;
  u16* wout_t = ws + OFF_WOUTT;
  u16* Qb = ws + OFF_Q;
  u16* Kb = ws + OFF_K;
  u16* XbYb = ws + OFF_XY;      // Xb (bf16 x), later reused as Yb
  u16* Vtb = (u16*)d_out;       // V^T scratch inside fp32 d_out
  float* out = (float*)d_out;

  prep_mask_k<<<32, 256, 0, stream>>>(ids_raw, maskf);
  cvt_x_k<<<4096, 256, 0, stream>>>(x, XbYb);
  transpose_cvt_k<<<dim3(96, 32), dim3(32, 8), 0, stream>>>(wqkv, wqkv_t, 1024, 3072);
  transpose_cvt_k<<<dim3(32, 32), dim3(32, 8), 0, stream>>>(wout, wout_t, 1024, 1024);
  gemm_qkv_kernel<<<dim3(24, 64), 256, 0, stream>>>(XbYb, wqkv_t, Qb, Kb, Vtb);
  attn_kernel<<<1024, 256, 0, stream>>>(Qb, Kb, Vtb, maskf, XbYb);
  gemm_out_kernel<<<dim3(8, 64), 256, 0, stream>>>(XbYb, wout_t, bias, out);
}

// Round 9
// 283.463 us; speedup vs baseline: 1.9396x; 1.0008x over previous
//
#include <hip/hip_runtime.h>
#include <hip/hip_bf16.h>
#include <stdint.h>

// Problem constants
#define Hn 16
#define Tn 2048
#define En 1024
#define Dh 64

typedef __bf16 bf16x8 __attribute__((ext_vector_type(8)));
typedef float f32x4 __attribute__((ext_vector_type(4)));
typedef unsigned short u16;
typedef u16 u16x8 __attribute__((ext_vector_type(8)));

#define SCALE_Q 0.18033688f   // log2(e)/8 folded into Q at projection time

// hardware RNE convert (R16)
__device__ __forceinline__ u16 f2bf(float f) {
  __bf16 b = (__bf16)f;
  return __builtin_bit_cast(u16, b);
}

typedef const __attribute__((address_space(1))) void gvoid_t;
typedef __attribute__((address_space(3))) void lvoid_t;
__device__ __forceinline__ void gl_lds16(const void* g, void* l) {
  __builtin_amdgcn_global_load_lds((gvoid_t*)g, (lvoid_t*)l, 16, 0, 0);
}

// ---------------------------------------------------------------------------
// x (fp32) -> bf16. 8M elements, 4096 blocks x 256 thr x 8.
// ---------------------------------------------------------------------------
__global__ void cvt_x_k(const float* __restrict__ in, u16* __restrict__ out) {
  int i = (blockIdx.x * 256 + threadIdx.x) * 8;
  float4 a = *(const float4*)(in + i);
  float4 b = *(const float4*)(in + i + 4);
  u16x8 o;
  o[0] = f2bf(a.x); o[1] = f2bf(a.y); o[2] = f2bf(a.z); o[3] = f2bf(a.w);
  o[4] = f2bf(b.x); o[5] = f2bf(b.y); o[6] = f2bf(b.z); o[7] = f2bf(b.w);
  *(u16x8*)(out + i) = o;
}

// ---------------------------------------------------------------------------
// Weight transpose fp32 -> bf16: out[c*R + r] = bf16(in[r*C + c])
// ---------------------------------------------------------------------------
__global__ void transpose_cvt_k(const float* __restrict__ in, u16* __restrict__ out,
                                int R, int C) {
  __shared__ float tile[32][33];
  int c0 = blockIdx.x * 32, r0 = blockIdx.y * 32;
  for (int i = threadIdx.y; i < 32; i += 8)
    tile[i][threadIdx.x] = in[(size_t)(r0 + i) * C + c0 + threadIdx.x];
  __syncthreads();
  for (int i = threadIdx.y; i < 32; i += 8)
    out[(size_t)(c0 + i) * R + r0 + threadIdx.x] = f2bf(tile[threadIdx.x][i]);
}

// ---------------------------------------------------------------------------
// R17: ids -> bf16 key mask (0x0000 keep / bf16(-1e30) pad). bf16 is exact
// for both values through the exp2 path (exp2(-9.97e29) = 0 = exp2(-1e30)).
// ---------------------------------------------------------------------------
__global__ void prep_mask_k(const int* __restrict__ in, u16* __restrict__ maskh) {
  __shared__ int is64_s;
  if (threadIdx.x == 0) {
    int all0 = 1;
    for (int i = 1; i < 256; i += 2) all0 &= (in[i] == 0);
    is64_s = all0;
  }
  __syncthreads();
  int i = blockIdx.x * 256 + threadIdx.x;
  int v = is64_s ? in[2 * i] : in[i];
  maskh[i] = (v != 0) ? (u16)0 : f2bf(-1e30f);
}

// ---------------------------------------------------------------------------
// R16 GEMM mainloop: BK=64, rule-#21 XOR swizzle (kept from R16; measured
// ~neutral — GEMMs sit at the m97-structure barrier-drain ceiling, not
// bank-conflict-bound).  C[128,128] += A[m0:.,:K] * Bt[n0:.,:K]^T  (bf16)
// ---------------------------------------------------------------------------
__device__ __forceinline__ void gemm_mainloop(const u16* __restrict__ A,
                                              const u16* __restrict__ Bt,
                                              int K, int m0, int n0,
                                              u16* lds, f32x4 acc[4][4]) {
  const int tid = threadIdx.x;
  const int lane = tid & 63;
  const int w = tid >> 6;
  const int wm = (w >> 1) * 64, wn = (w & 1) * 64;
  const int quad = lane >> 4, ln = lane & 15;

  const int e0 = w * 512 + lane * 8;          // 0..2047; wave-uniform + lane*16B
  const int r0 = e0 >> 6;                     // source row 0..31 within chunk
  const int cS = (e0 & 63) ^ ((r0 & 7) * 8);  // pre-swizzled source col

  const u16* gA = A + (size_t)(m0 + r0) * K + cS;
  const u16* gB = Bt + (size_t)(n0 + r0) * K + cS;
  u16* lA = lds + e0;
  u16* lB = lds + 8192 + e0;
  const int xA = (ln & 7) * 8;                // read-side XOR ((row&7)*8)

  for (int k0 = 0; k0 < K; k0 += 64) {
#pragma unroll
    for (int c = 0; c < 4; c++) {             // 4 row-chunks of 32 for A and B
      gl_lds16(gA + (size_t)(c * 32) * K + k0, lA + c * 2048);
      gl_lds16(gB + (size_t)(c * 32) * K + k0, lB + c * 2048);
    }
    __syncthreads();
#pragma unroll
    for (int kk = 0; kk < 2; kk++) {
      bf16x8 af[4], bfr[4];
#pragma unroll
      for (int mt = 0; mt < 4; mt++)
        af[mt] = *(const bf16x8*)(lds + (wm + mt * 16 + ln) * 64 +
                                  ((kk * 32 + quad * 8) ^ xA));
#pragma unroll
      for (int nt = 0; nt < 4; nt++)
        bfr[nt] = *(const bf16x8*)(lds + 8192 + (wn + nt * 16 + ln) * 64 +
                                   ((kk * 32 + quad * 8) ^ xA));
#pragma unroll
      for (int mt = 0; mt < 4; mt++)
#pragma unroll
        for (int nt = 0; nt < 4; nt++)
          acc[mt][nt] = __builtin_amdgcn_mfma_f32_16x16x32_bf16(af[mt], bfr[nt],
                                                                acc[mt][nt], 0, 0, 0);
    }
    __syncthreads();
  }
}

// ---------------------------------------------------------------------------
// GEMM 1: qkv = X @ Wqkv. Q (pre-scaled log2e/8) and K scatter directly;
// V-blocks stage the C-tile in LDS and write Vt[B,H,D,T] rows COALESCED.
// ---------------------------------------------------------------------------
__global__ __launch_bounds__(256, 3)
void gemm_qkv_kernel(const u16* __restrict__ X, const u16* __restrict__ Wt,
                     u16* __restrict__ Qo, u16* __restrict__ Ko,
                     u16* __restrict__ Vto) {
  __shared__ __align__(16) u16 lds[128 * 130];   // staging 16384 + epilogue 16640
  const int m0 = blockIdx.y * 128, n0 = blockIdx.x * 128;
  f32x4 acc[4][4];
#pragma unroll
  for (int i = 0; i < 4; i++)
#pragma unroll
    for (int j = 0; j < 4; j++) acc[i][j] = (f32x4){0.f, 0.f, 0.f, 0.f};

  gemm_mainloop(X, Wt, En, m0, n0, lds, acc);

  const int tid = threadIdx.x, lane = tid & 63, w = tid >> 6;
  const int wm = (w >> 1) * 64, wn = (w & 1) * 64;
  const int quad = lane >> 4, ln = lane & 15;
  const int which = n0 >> 10;  // block-uniform: 0=Q 1=K 2=V
  const int bb = m0 >> 11, t0 = m0 & (Tn - 1);

  if (which < 2) {
#pragma unroll
    for (int mt = 0; mt < 4; mt++)
#pragma unroll
      for (int nt = 0; nt < 4; nt++)
#pragma unroll
        for (int r = 0; r < 4; r++) {
          int t = t0 + wm + mt * 16 + quad * 4 + r;   // C row = quad*4+reg
          int ng = n0 + wn + nt * 16 + ln;            // C col = lane&15
          int e = ng & (En - 1);
          int h = e >> 6, d = e & 63;
          size_t bh = (size_t)(bb * Hn + h);
          if (which == 0)
            Qo[(bh * Tn + t) * Dh + d] = f2bf(acc[mt][nt][r] * SCALE_Q);
          else
            Ko[(bh * Tn + t) * Dh + d] = f2bf(acc[mt][nt][r]);
        }
  } else {
    // stage C-tile -> LDS [128 rows(t)][130 stride, 128 cols(e)]
#pragma unroll
    for (int mt = 0; mt < 4; mt++)
#pragma unroll
      for (int nt = 0; nt < 4; nt++)
#pragma unroll
        for (int r = 0; r < 4; r++)
          lds[(wm + mt * 16 + quad * 4 + r) * 130 + wn + nt * 16 + ln] =
              f2bf(acc[mt][nt][r]);
    __syncthreads();
    const int ebase = n0 & (En - 1);
    // each wave writes 32 d-rows of Vt; lane covers t = lane and lane+64
#pragma unroll
    for (int i = 0; i < 32; i++) {
      int col = w * 32 + i;
      int e = ebase + col;
      int hh = e >> 6, d = e & 63;
      size_t vrow = (((size_t)(bb * Hn + hh)) * Dh + d) * Tn + t0;
      Vto[vrow + lane] = lds[lane * 130 + col];
      Vto[vrow + 64 + lane] = lds[(64 + lane) * 130 + col];
    }
  }
}

// ---------------------------------------------------------------------------
// GEMM 2: out = Y @ Wout + bias  -> fp32 output.
// ---------------------------------------------------------------------------
__global__ __launch_bounds__(256, 3)
void gemm_out_kernel(const u16* __restrict__ Y, const u16* __restrict__ Wt,
                     const float* __restrict__ bias, float* __restrict__ Out) {
  __shared__ __align__(16) u16 lds[16384];
  const int m0 = blockIdx.y * 128, n0 = blockIdx.x * 128;
  f32x4 acc[4][4];
#pragma unroll
  for (int i = 0; i < 4; i++)
#pragma unroll
    for (int j = 0; j < 4; j++) acc[i][j] = (f32x4){0.f, 0.f, 0.f, 0.f};

  gemm_mainloop(Y, Wt, En, m0, n0, lds, acc);

  const int tid = threadIdx.x, lane = tid & 63, w = tid >> 6;
  const int wm = (w >> 1) * 64, wn = (w & 1) * 64;
  const int quad = lane >> 4, ln = lane & 15;

#pragma unroll
  for (int mt = 0; mt < 4; mt++)
#pragma unroll
    for (int nt = 0; nt < 4; nt++)
#pragma unroll
      for (int r = 0; r < 4; r++) {
        int mg = m0 + wm + mt * 16 + quad * 4 + r;
        int ng = n0 + wn + nt * 16 + ln;
        Out[(size_t)mg * En + ng] = acc[mt][nt][r] + bias[ng];
      }
}

// ---------------------------------------------------------------------------
// Flash attention, R17 = R16 structure (97us) + two attn-local changes:
//
// 1) Mask via LDS: bf16 mask row (4KB) staged ONCE per block with one
//    gl_lds16/thread. Removes the last exposed global latency — the 4
//    per-tile mrow f32 loads were consumed ~10 insts after issue with no
//    cover (K is LDS-staged, V is exp-covered). Now a ds_read_u16 in the
//    same lgkmcnt window as the K ds_reads. Bit-exact.
//    LDS total 39.9KB -> still exactly 4 blocks/CU.
//
// 2) lsum via ones-MFMA: row-sums of P computed by the matrix pipe
//    (B = all-ones, 4 extra MFMA/tile) instead of 32 v_add/tile/thread;
//    C-layout row matches O exactly, so the epilogue 16-lane shfl reduce
//    is deleted too. Denominator = sum of bf16(p) — consistent with the
//    bf16 numerator (PV). If absmax trips tolerance, revert just this.
// ---------------------------------------------------------------------------
__global__ __launch_bounds__(256, 3)
void attn_kernel(const u16* __restrict__ Q, const u16* __restrict__ K,
                 const u16* __restrict__ Vt, const u16* __restrict__ maskh,
                 u16* __restrict__ Y) {
  __shared__ __align__(16) u16 Pl[128 * 76];
  __shared__ __align__(16) u16 KL[2 * 4096];   // 2 x 8KB K tiles (src-swizzled)
  __shared__ __align__(16) u16 ML[2048];       // bf16 mask row (4KB)

  const int bid = blockIdx.x;
  const int g = bid >> 8, sq = (bid >> 6) & 3;
  int qt;
  if (g == 0)      qt = 15 - sq;
  else if (g == 1) qt = sq;
  else if (g == 2) qt = 11 - sq;
  else             qt = 4 + sq;
  const int bh = bid & 63;
  const int b = bh >> 4, h = bh & 15;
  const int tid = threadIdx.x, lane = tid & 63, w = tid >> 6;
  const int quad = lane >> 4, ln = lane & 15;
  const int qb = w * 32;
  const int g0 = qt * 128 + qb;       // first q row of this wave

  const size_t baseQK = (size_t)bh * (Tn * Dh);
  const size_t baseV = (size_t)bh * (Dh * Tn);
  const u16* Kp = K + baseQK;

  // staging addresses: thread covers rows srow and srow+32, swizzled col.
  const int srow = tid >> 3;
  const int scol = ((tid & 7) * 8) ^ ((srow & 7) * 8);
  const u16* gK0 = Kp + (size_t)srow * Dh + scol;
  const u16* gK1 = Kp + (size_t)(srow + 32) * Dh + scol;
  u16* lK0 = KL + tid * 8;
  u16* lK1 = lK0 + 2048;

  auto stage = [&](int buf, int k0) {
    gl_lds16(gK0 + (size_t)k0 * Dh, lK0 + buf * 4096);
    gl_lds16(gK1 + (size_t)k0 * Dh, lK1 + buf * 4096);
  };

  // stage the whole bf16 mask row once (256 thr x 16B = 4KB)
  gl_lds16(maskh + (size_t)b * Tn + tid * 8, ML + tid * 8);

  // Q fragments (pre-scaled) in registers for the whole kernel
  bf16x8 aq[2][2];
#pragma unroll
  for (int rt = 0; rt < 2; rt++)
#pragma unroll
    for (int ks = 0; ks < 2; ks++)
      aq[rt][ks] = *(const bf16x8*)(Q + baseQK +
          (size_t)(g0 + rt * 16 + ln) * Dh + ks * 32 + quad * 8);

  // all-ones B fragment for the row-sum MFMA
  bf16x8 onesb;
#pragma unroll
  for (int i = 0; i < 8; i++) onesb[i] = (__bf16)1.0f;

  f32x4 O[2][4];
  f32x4 ls[2];
#pragma unroll
  for (int rt = 0; rt < 2; rt++) {
#pragma unroll
    for (int dt = 0; dt < 4; dt++) O[rt][dt] = (f32x4){0.f, 0.f, 0.f, 0.f};
    ls[rt] = (f32x4){0.f, 0.f, 0.f, 0.f};
  }

  auto tile = [&](const u16* kl, int k0, bool dg) {
    // ---- phase 1: K fragments + mask from LDS + QK^T (mask in C-in) ----
    f32x4 s[2][4];
    {
      bf16x8 bk[4][2];
      float kvf[4];
#pragma unroll
      for (int ct = 0; ct < 4; ct++) {
        kvf[ct] = __builtin_bit_cast(float,
                      (uint32_t)ML[k0 + ct * 16 + ln] << 16);
#pragma unroll
        for (int ks = 0; ks < 2; ks++)
          bk[ct][ks] = *(const bf16x8*)(kl + (ct * 16 + ln) * 64 +
                                        ((ks * 32 + quad * 8) ^ ((ln & 7) * 8)));
      }
#pragma unroll
      for (int rt = 0; rt < 2; rt++)
#pragma unroll
        for (int ct = 0; ct < 4; ct++)
          s[rt][ct] = (f32x4){kvf[ct], kvf[ct], kvf[ct], kvf[ct]};
      __builtin_amdgcn_s_setprio(1);
#pragma unroll
      for (int ks = 0; ks < 2; ks++)
#pragma unroll
        for (int rt = 0; rt < 2; rt++)
#pragma unroll
          for (int ct = 0; ct < 4; ct++)
            s[rt][ct] = __builtin_amdgcn_mfma_f32_16x16x32_bf16(aq[rt][ks], bk[ct][ks],
                                                                s[rt][ct], 0, 0, 0);
      __builtin_amdgcn_s_setprio(0);
    }  // bk dead here

    // ---- phase 2: V fragments issued, latency hidden behind exp ----
    bf16x8 bv[4][2];
#pragma unroll
    for (int dt = 0; dt < 4; dt++)
#pragma unroll
      for (int ks = 0; ks < 2; ks++)
        bv[dt][ks] = *(const bf16x8*)(Vt + baseV +
            (size_t)(dt * 16 + ln) * Tn + k0 + ks * 32 + quad * 8);

#pragma unroll
    for (int rt = 0; rt < 2; rt++) {
      if (dg) {
#pragma unroll
        for (int ct = 0; ct < 4; ct++)
#pragma unroll
          for (int r = 0; r < 4; r++) {
            int qg = g0 + rt * 16 + quad * 4 + r;
            int kg = k0 + ct * 16 + ln;
            float v = (kg > qg) ? -1e30f : s[rt][ct][r];
            float p = exp2f(fminf(v, 126.f));
            Pl[(qb + rt * 16 + quad * 4 + r) * 76 + ct * 16 + ln] = f2bf(p);
          }
      } else {
#pragma unroll
        for (int ct = 0; ct < 4; ct++)
#pragma unroll
          for (int r = 0; r < 4; r++) {
            float p = exp2f(fminf(s[rt][ct][r], 126.f));
            Pl[(qb + rt * 16 + quad * 4 + r) * 76 + ct * 16 + ln] = f2bf(p);
          }
      }
    }

    // ---- phase 3: O += P V ; ls += P 1 (row sums via matrix pipe) ----
    __builtin_amdgcn_s_setprio(1);
#pragma unroll
    for (int ks2 = 0; ks2 < 2; ks2++)
#pragma unroll
      for (int rt = 0; rt < 2; rt++) {
        bf16x8 ap = *(const bf16x8*)(Pl + (qb + rt * 16 + ln) * 76 + ks2 * 32 + quad * 8);
#pragma unroll
        for (int dt = 0; dt < 4; dt++)
          O[rt][dt] = __builtin_amdgcn_mfma_f32_16x16x32_bf16(ap, bv[dt][ks2],
                                                              O[rt][dt], 0, 0, 0);
        ls[rt] = __builtin_amdgcn_mfma_f32_16x16x32_bf16(ap, onesb,
                                                         ls[rt], 0, 0, 0);
      }
    __builtin_amdgcn_s_setprio(0);
  };

  const int nfull = g0 >> 6;          // per-wave: 2qt (w<2) or 2qt+1 (w>=2)
  const int NT = 2 * qt + 1;          // uniform last iteration index
  stage(0, 0);
  int cur = 0;
  for (int kt = 0; kt <= NT; kt++) {
    __syncthreads();                  // staged K(kt) + ML ready; buf[cur^1] free
    if (kt < NT) stage(cur ^ 1, (kt + 1) * 64);
    if (kt < nfull)       tile(KL + cur * 4096, kt * 64, false);
    else if (kt == nfull) tile(KL + cur * 4096, kt * 64, true);
    // else: waves 0,1 idle on the final iteration (barrier-participating)
    cur ^= 1;
  }

  // epilogue: ls[rt][r] already holds the row sum (same C-layout as O)
#pragma unroll
  for (int rt = 0; rt < 2; rt++)
#pragma unroll
    for (int r = 0; r < 4; r++) {
      float inv = 1.f / ls[rt][r];
      int tg = g0 + rt * 16 + quad * 4 + r;
      size_t ob = ((size_t)b * Tn + tg) * En + h * Dh;
#pragma unroll
      for (int dt = 0; dt < 4; dt++)
        Y[ob + dt * 16 + ln] = f2bf(O[rt][dt][r] * inv);
    }
}

// ---------------------------------------------------------------------------
// Workspace (u16 units), ~58.8 MB. Vt scratch lives in d_out (dead before
// gemm_out overwrites it — stream-ordered).
// ---------------------------------------------------------------------------
#define OFF_MASK  0                       // 8192 u16 bf16 mask (16KB region)
#define OFF_WQKVT 16384
#define OFF_WOUTT (OFF_WQKVT + 3145728)
#define OFF_Q     (OFF_WOUTT + 1048576)
#define OFF_K     (OFF_Q + 8388608)
#define OFF_XY    (OFF_K + 8388608)

extern "C" void kernel_launch(void* const* d_in, const int* in_sizes, int n_in,
                              void* d_out, int out_size, void* d_ws, size_t ws_size,
                              hipStream_t stream) {
  const float* x = nullptr;      // 8388608
  const int* ids_raw = nullptr;  // 8192
  const float* wqkv = nullptr;   // 3145728
  const float* wout = nullptr;   // 1048576
  const float* bias = nullptr;   // 1024
  for (int i = 0; i < n_in; i++) {
    switch (in_sizes[i]) {
      case 8388608: x = (const float*)d_in[i]; break;
      case 8192:    ids_raw = (const int*)d_in[i]; break;
      case 3145728: wqkv = (const float*)d_in[i]; break;
      case 1048576: wout = (const float*)d_in[i]; break;
      case 1024:    bias = (const float*)d_in[i]; break;
      default: break;
    }
  }
  if (!x) x = (const float*)d_in[0];
  if (!ids_raw) ids_raw = (const int*)d_in[1];
  if (!wqkv) wqkv = (const float*)d_in[2];
  if (!wout) wout = (const float*)d_in[3];
  if (!bias) bias = (const float*)d_in[4];

  u16* ws = (u16*)d_ws;
  u16* maskh = ws + OFF_MASK;
  u16* wqkv_t = ws + OFF_WQKVT;
  u16* wout_t = ws + OFF_WOUTT;
  u16* Qb = ws + OFF_Q;
  u16* Kb = ws + OFF_K;
  u16* XbYb = ws + OFF_XY;      // Xb (bf16 x), later reused as Yb
  u16* Vtb = (u16*)d_out;       // V^T scratch inside fp32 d_out
  float* out = (float*)d_out;

  prep_mask_k<<<32, 256, 0, stream>>>(ids_raw, maskh);
  cvt_x_k<<<4096, 256, 0, stream>>>(x, XbYb);
  transpose_cvt_k<<<dim3(96, 32), dim3(32, 8), 0, stream>>>(wqkv, wqkv_t, 1024, 3072);
  transpose_cvt_k<<<dim3(32, 32), dim3(32, 8), 0, stream>>>(wout, wout_t, 1024, 1024);
  gemm_qkv_kernel<<<dim3(24, 64), 256, 0, stream>>>(XbYb, wqkv_t, Qb, Kb, Vtb);
  attn_kernel<<<1024, 256, 0, stream>>>(Qb, Kb, Vtb, maskh, XbYb);
  gemm_out_kernel<<<dim3(8, 64), 256, 0, stream>>>(XbYb, wout_t, bias, out);
}